// Round 2
// baseline (249.198 us; speedup 1.0000x reference)
//
#include <hip/hip_runtime.h>

// EMA scan: out[:,0,:] = x[:,0,:]; out[:,t,:] = 0.1*x[:,t,:] + 0.9*out[:,t-1,:]
// x: (16, 4096, 512) fp32.
//
// Strategy: chunk the T axis. The recurrence forgets at 0.9^W, so each chunk
// reconstructs its carry with a W=64 warm-up from zero (error <= 0.9^64 * |y|
// ~ 1.6e-3; measured absmax 0.0039, threshold 7.6e-2). No inter-block comms.
//
// R1 change: L 256 -> 64. Previous config was latency-bound (Occupancy 4.5%,
// 2 waves/CU, HBM at 31% peak, VALU 1.6%). L=64 quadruples thread count to
// 131072 -> 8 waves/CU, giving ~4x the loads in flight per CU. Warm-up read
// overhead rises to 100% of input, but the 128 MiB input is L3-resident
// (FETCH_SIZE 79MB < 160MB read volume already showed L3 absorption), so the
// extra reads are cheap. Output stores are non-temporal to avoid evicting the
// input from L3.
// R2: fix compile — __builtin_nontemporal_store needs a native vector type,
// not HIP's float4 class; store through an ext_vector_type(4) alias.

constexpr int B = 16;
constexpr int T = 4096;
constexpr int D = 512;
constexpr int DV = D / 4;      // 128 float4 columns per (b, t) row
constexpr int L = 64;          // chunk length along T (was 256)
constexpr int C = T / L;       // 64 chunks
constexpr int W = 64;          // warm-up steps (0.9^64 ~ 1.2e-3)
constexpr int UNR = 8;         // loads in flight per wave

typedef float vfloat4 __attribute__((ext_vector_type(4)));

__global__ __launch_bounds__(256)
void ema_chunked_kernel(const float4* __restrict__ X, float4* __restrict__ O) {
    const int g     = blockIdx.x * 256 + threadIdx.x;
    const int dvec  = g & (DV - 1);          // consecutive within wave -> coalesced
    const int chunk = (g >> 7) & (C - 1);    // DV = 128 = 1<<7
    const int b     = g >> 13;               // DV*C = 8192 = 1<<13

    const float a  = 0.1f;
    const float bb = 0.9f;

    const int base = b * (T * DV) + dvec;    // max ~7.9M float4, fits int
    const int t0   = chunk * L;

    float4 y;
    if (chunk == 0) {
        // y_init = x0: main-loop step at t=0 gives 0.1*x0 + 0.9*x0 = x0 exactly.
        y = X[base];
    } else {
        y = make_float4(0.f, 0.f, 0.f, 0.f);
        const float4* xp = X + base + (t0 - W) * DV;
        for (int tt = 0; tt < W; tt += UNR) {
            float4 v[UNR];
            #pragma unroll
            for (int j = 0; j < UNR; ++j) v[j] = xp[(tt + j) * DV];
            #pragma unroll
            for (int j = 0; j < UNR; ++j) {
                y.x = fmaf(bb, y.x, a * v[j].x);
                y.y = fmaf(bb, y.y, a * v[j].y);
                y.z = fmaf(bb, y.z, a * v[j].z);
                y.w = fmaf(bb, y.w, a * v[j].w);
            }
        }
    }

    const float4* xp = X + base + t0 * DV;
    float4*       op = O + base + t0 * DV;
    for (int tt = 0; tt < L; tt += UNR) {
        float4 v[UNR];
        #pragma unroll
        for (int j = 0; j < UNR; ++j) v[j] = xp[(tt + j) * DV];
        #pragma unroll
        for (int j = 0; j < UNR; ++j) {
            y.x = fmaf(bb, y.x, a * v[j].x);
            y.y = fmaf(bb, y.y, a * v[j].y);
            y.z = fmaf(bb, y.z, a * v[j].z);
            y.w = fmaf(bb, y.w, a * v[j].w);
            vfloat4 yv;
            yv.x = y.x; yv.y = y.y; yv.z = y.z; yv.w = y.w;
            __builtin_nontemporal_store(yv,
                reinterpret_cast<vfloat4*>(&op[(tt + j) * DV]));
        }
    }
}

extern "C" void kernel_launch(void* const* d_in, const int* in_sizes, int n_in,
                              void* d_out, int out_size, void* d_ws, size_t ws_size,
                              hipStream_t stream) {
    const float4* X = (const float4*)d_in[0];
    float4*       O = (float4*)d_out;

    const int total_threads = B * C * DV;    // 131072
    const int block = 256;
    const int grid  = total_threads / block; // 512 blocks -> 8 waves/CU
    ema_chunked_kernel<<<grid, block, 0, stream>>>(X, O);
}

// Round 3
// 240.699 us; speedup vs baseline: 1.0353x; 1.0353x over previous
//
#include <hip/hip_runtime.h>

// EMA scan: out[:,0,:] = x[:,0,:]; out[:,t,:] = 0.1*x[:,t,:] + 0.9*out[:,t-1,:]
// x: (16, 4096, 512) fp32.
//
// Strategy: chunk the T axis. The recurrence forgets at 0.9^W, so each chunk
// reconstructs its carry with a W=64 warm-up from zero (error <= 0.9^64 * |y|
// ~ 1.6e-3; measured absmax 0.0039, threshold 7.6e-2). No inter-block comms.
//
// R3: back to L=256 (min HBM traffic: warm-up = 25% of input; R2's L=64 cost
// +49 MB HBM fetch and lost more than its +10% BW gain). R0->R2 showed wave
// count is NOT the lever (4x waves -> +10% BW). New theory: each wave is
// stop-and-go (load batch -> drain -> compute -> store), so loads sit in
// flight only ~150-250 cyc of every ~900+ cyc HBM round-trip. Fix: explicit
// A/B double-buffered prefetch, UNR=16 -> 16 KB/wave continuously in flight,
// independent of wave count.

constexpr int B = 16;
constexpr int T = 4096;
constexpr int D = 512;
constexpr int DV = D / 4;      // 128 float4 columns per (b, t) row
constexpr int L = 256;         // chunk length along T
constexpr int C = T / L;       // 16 chunks
constexpr int W = 64;          // warm-up steps (0.9^64 ~ 1.2e-3)
constexpr int UNR = 16;        // batch size; 2 batches resident (A/B)

__global__ __launch_bounds__(64)
void ema_chunked_kernel(const float4* __restrict__ X, float4* __restrict__ O) {
    const int g     = blockIdx.x * 64 + threadIdx.x;
    const int dvec  = g & (DV - 1);          // consecutive within wave -> coalesced
    const int chunk = (g >> 7) & (C - 1);    // DV = 128 = 1<<7
    const int b     = g >> 11;               // DV*C = 2048 = 1<<11

    const float a  = 0.1f;
    const float bb = 0.9f;

    const int base = b * (T * DV) + dvec;    // max ~8.4M float4, fits int
    const int t0   = chunk * L;

    float4 va[UNR], vb[UNR];
    float4 y;

    if (chunk == 0) {
        // y_init = x0: main-loop step at t=0 gives 0.1*x0 + 0.9*x0 = x0 exactly.
        y = X[base];
    } else {
        // Warm-up from zero over [t0-W, t0), software-pipelined, no stores.
        y = make_float4(0.f, 0.f, 0.f, 0.f);
        const float4* wp = X + base + (t0 - W) * DV;
        #pragma unroll
        for (int j = 0; j < UNR; ++j) va[j] = wp[j * DV];
        for (int tt = 0; tt < W - 2 * UNR; tt += 2 * UNR) {
            #pragma unroll
            for (int j = 0; j < UNR; ++j) vb[j] = wp[(tt + UNR + j) * DV];
            #pragma unroll
            for (int j = 0; j < UNR; ++j) {
                y.x = fmaf(bb, y.x, a * va[j].x);
                y.y = fmaf(bb, y.y, a * va[j].y);
                y.z = fmaf(bb, y.z, a * va[j].z);
                y.w = fmaf(bb, y.w, a * va[j].w);
            }
            #pragma unroll
            for (int j = 0; j < UNR; ++j) va[j] = wp[(tt + 2 * UNR + j) * DV];
            #pragma unroll
            for (int j = 0; j < UNR; ++j) {
                y.x = fmaf(bb, y.x, a * vb[j].x);
                y.y = fmaf(bb, y.y, a * vb[j].y);
                y.z = fmaf(bb, y.z, a * vb[j].z);
                y.w = fmaf(bb, y.w, a * vb[j].w);
            }
        }
        // Tail: va holds [W-32, W-16); load+consume [W-16, W).
        #pragma unroll
        for (int j = 0; j < UNR; ++j) vb[j] = wp[(W - UNR + j) * DV];
        #pragma unroll
        for (int j = 0; j < UNR; ++j) {
            y.x = fmaf(bb, y.x, a * va[j].x);
            y.y = fmaf(bb, y.y, a * va[j].y);
            y.z = fmaf(bb, y.z, a * va[j].z);
            y.w = fmaf(bb, y.w, a * va[j].w);
        }
        #pragma unroll
        for (int j = 0; j < UNR; ++j) {
            y.x = fmaf(bb, y.x, a * vb[j].x);
            y.y = fmaf(bb, y.y, a * vb[j].y);
            y.z = fmaf(bb, y.z, a * vb[j].z);
            y.w = fmaf(bb, y.w, a * vb[j].w);
        }
    }

    // Main loop over [t0, t0+L), A/B pipelined: while computing one batch of
    // 16, the next 16 loads are already issued -> ~16 KB/wave in flight.
    const float4* xp = X + base + t0 * DV;
    float4*       op = O + base + t0 * DV;

    #pragma unroll
    for (int j = 0; j < UNR; ++j) va[j] = xp[j * DV];

    for (int tt = 0; tt < L - 2 * UNR; tt += 2 * UNR) {
        #pragma unroll
        for (int j = 0; j < UNR; ++j) vb[j] = xp[(tt + UNR + j) * DV];
        #pragma unroll
        for (int j = 0; j < UNR; ++j) {
            y.x = fmaf(bb, y.x, a * va[j].x);
            y.y = fmaf(bb, y.y, a * va[j].y);
            y.z = fmaf(bb, y.z, a * va[j].z);
            y.w = fmaf(bb, y.w, a * va[j].w);
            op[(tt + j) * DV] = y;
        }
        #pragma unroll
        for (int j = 0; j < UNR; ++j) va[j] = xp[(tt + 2 * UNR + j) * DV];
        #pragma unroll
        for (int j = 0; j < UNR; ++j) {
            y.x = fmaf(bb, y.x, a * vb[j].x);
            y.y = fmaf(bb, y.y, a * vb[j].y);
            y.z = fmaf(bb, y.z, a * vb[j].z);
            y.w = fmaf(bb, y.w, a * vb[j].w);
            op[(tt + UNR + j) * DV] = y;
        }
    }
    // Tail: va holds [L-32, L-16); load+consume [L-16, L).
    constexpr int TL = L - 2 * UNR;
    #pragma unroll
    for (int j = 0; j < UNR; ++j) vb[j] = xp[(TL + UNR + j) * DV];
    #pragma unroll
    for (int j = 0; j < UNR; ++j) {
        y.x = fmaf(bb, y.x, a * va[j].x);
        y.y = fmaf(bb, y.y, a * va[j].y);
        y.z = fmaf(bb, y.z, a * va[j].z);
        y.w = fmaf(bb, y.w, a * va[j].w);
        op[(TL + j) * DV] = y;
    }
    #pragma unroll
    for (int j = 0; j < UNR; ++j) {
        y.x = fmaf(bb, y.x, a * vb[j].x);
        y.y = fmaf(bb, y.y, a * vb[j].y);
        y.z = fmaf(bb, y.z, a * vb[j].z);
        y.w = fmaf(bb, y.w, a * vb[j].w);
        op[(TL + UNR + j) * DV] = y;
    }
}

extern "C" void kernel_launch(void* const* d_in, const int* in_sizes, int n_in,
                              void* d_out, int out_size, void* d_ws, size_t ws_size,
                              hipStream_t stream) {
    const float4* X = (const float4*)d_in[0];
    float4*       O = (float4*)d_out;

    const int total_threads = B * C * DV;    // 32768
    const int block = 64;
    const int grid  = total_threads / block; // 512 blocks -> 2 blocks/CU
    ema_chunked_kernel<<<grid, block, 0, stream>>>(X, O);
}